// Round 7
// baseline (491.498 us; speedup 1.0000x reference)
//
#include <hip/hip_runtime.h>
#include <hip/hip_bf16.h>

#define N_TOK 16384
#define DIM   128
#define JT     64      // K/V tile (j) per iteration

// LDS row strides (shorts), unpadded + XOR swizzle (T2).
#define KROW 128       // kbuf rows: 64      swizzle: 16B-seg ^= (row&7)
#define VROW 64        // vbuf rows: 128     swizzle: 16B-seg ^= (row&7)
#define PROW 32        // pbuf rows: 64/wave swizzle: 16B-seg ^= ((row>>1)&3)

using bf16x8 = __attribute__((ext_vector_type(8))) short;   // 8 bf16 = 4 VGPRs (MFMA A/B frag)
using f32x4  = __attribute__((ext_vector_type(4))) float;   // MFMA C/D frag

static __device__ __forceinline__ unsigned short f2b(float f) {
    union { __hip_bfloat16 h; unsigned short u; } cv;
    cv.h = __float2bfloat16(f);   // RNE
    return cv.u;
}

static __device__ __forceinline__ bf16x8 load8f(const float* p) {
    float4 a = *reinterpret_cast<const float4*>(p);
    float4 b = *reinterpret_cast<const float4*>(p + 4);
    bf16x8 r;
    r[0] = (short)f2b(a.x); r[1] = (short)f2b(a.y);
    r[2] = (short)f2b(a.z); r[3] = (short)f2b(a.w);
    r[4] = (short)f2b(b.x); r[5] = (short)f2b(b.y);
    r[6] = (short)f2b(b.z); r[7] = (short)f2b(b.w);
    return r;
}

// ---------------------------------------------------------------------------
__global__ __launch_bounds__(256)
void marker_kernel(float* out, float val)
{
    int i = blockIdx.x * 256 + threadIdx.x;
    if (i < N_TOK * DIM) out[i] = val;
}

// ---------------------------------------------------------------------------
// QKV: Q = x@Wq^T, K = x@Wk^T, Vt = (x@Wv^T)^T.  fp32 in, bf16 out (ws).
// ---------------------------------------------------------------------------
__global__ __launch_bounds__(256)
void qkv_kernel(const float* __restrict__ x,
                const float* __restrict__ wq,
                const float* __restrict__ wk,
                const float* __restrict__ wv,
                unsigned short* __restrict__ Q,
                unsigned short* __restrict__ K,
                unsigned short* __restrict__ Vt)
{
    const int t = threadIdx.x;
    const int wave = t >> 6, lane = t & 63;
    const int ln = lane & 15, quad = lane >> 4, q8 = quad * 8;
    const int z = blockIdx.y;
    const float* W = (z == 0) ? wq : (z == 1) ? wk : wv;
    const int r0 = blockIdx.x * 64 + wave * 16;

    bf16x8 a[4];
#pragma unroll
    for (int ks = 0; ks < 4; ++ks)
        a[ks] = load8f(&x[(size_t)(r0 + ln) * DIM + ks * 32 + q8]);

    f32x4 acc[8];
#pragma unroll
    for (int nt = 0; nt < 8; ++nt) acc[nt] = f32x4{0.f, 0.f, 0.f, 0.f};

#pragma unroll
    for (int nt = 0; nt < 8; ++nt)
#pragma unroll
        for (int ks = 0; ks < 4; ++ks) {
            bf16x8 b = load8f(&W[(size_t)(nt * 16 + ln) * DIM + ks * 32 + q8]);
            acc[nt] = __builtin_amdgcn_mfma_f32_16x16x32_bf16(a[ks], b, acc[nt], 0, 0, 0);
        }

#pragma unroll
    for (int nt = 0; nt < 8; ++nt) {
        const int col = nt * 16 + ln;
        if (z == 2) {
            ushort4 v4;
            v4.x = f2b(acc[nt][0]); v4.y = f2b(acc[nt][1]);
            v4.z = f2b(acc[nt][2]); v4.w = f2b(acc[nt][3]);
            *reinterpret_cast<ushort4*>(&Vt[(size_t)col * N_TOK + r0 + quad * 4]) = v4;
        } else {
            unsigned short* dst = (z == 0) ? Q : K;
#pragma unroll
            for (int r = 0; r < 4; ++r)
                dst[(size_t)(r0 + quad * 4 + r) * DIM + col] = f2b(acc[nt][r]);
        }
    }
}

// ---------------------------------------------------------------------------
// Flash attention, fixed-offset softmax (exact: p = exp2(logit*log2e - 16)).
// v5: MT=4 — 4 waves x 256 threads, 64 Q-rows/wave, 256 Q-rows/block.
// grid (N/256, nsplit) = 256 blocks -> 1 block/CU, 1 wave/SIMD.
//
// Rationale (R6 post-mortem): v4 (MT=1, 8 waves) saturated LDS read BW
// (~110 B/cyc/CU vs ~112 ceiling) because each wave reads the full K/V
// tile regardless of how many Q-rows it owns.  LDS traffic per unit work
// scales 1/MT.  MT=4 halves traffic vs v3 (each 1KB K/V b128 read feeds
// 4 MFMA), putting the LDS floor (~1.4K cyc/tile) below the MFMA+VALU
// content.  1 wave/SIMD is enough to saturate the MFMA pipe (m233).
//
// Same v3/v4 single-barrier dbuf schedule (proven R5):
//   issue gloads(j+1) -> regs; QK^T(kb[c]); softmax+PV halves via pbuf;
//   ds_write bufs[c^1] <- regs; __syncthreads(); c^=1.
// ---------------------------------------------------------------------------
__global__ __launch_bounds__(256, 1)
void flash_kernel(const unsigned short* __restrict__ Q,
                  const unsigned short* __restrict__ K,
                  const unsigned short* __restrict__ Vt,
                  const unsigned int* __restrict__ u32,
                  int jspan,
                  float* __restrict__ pO, float* __restrict__ pl,
                  float* __restrict__ out)
{
    __shared__ unsigned short kb[2][JT * KROW];    // 32 KB
    __shared__ unsigned short vb[2][DIM * VROW];   // 32 KB
    __shared__ unsigned short pbuf[4][64 * PROW];  // 16 KB (4 KB/wave)
    __shared__ int ub[2][JT];                      // 512 B  -> 80.5 KB total

    const int t = threadIdx.x;
    const int wave = t >> 6, lane = t & 63;
    const int ln = lane & 15, quad = lane >> 4, q8 = quad * 8;
    const int r0 = blockIdx.x * 256 + wave * 64;
    const int split = blockIdx.y;
    const int j0 = split * jspan;
    const int j1 = j0 + jspan;

    const float lscale = 1.4426950408889634f * 0.08838834764831845f; // log2(e)/sqrt(128)
    const float cbias  = 5.0f * 1.4426950408889634f - 16.0f;         // same-user: 5*log2e - 16
    const float cnob   = -16.0f;                                     // different user

    // uid dtype sniff: identical verdict on every thread (uniform branch)
    bool i64 = true;
    for (int k = 0; k < 64; ++k) i64 = i64 && (u32[2 * k + 1] == 0u);

    bf16x8 qf[4][4];
    int uq[4][4];
#pragma unroll
    for (int mt = 0; mt < 4; ++mt) {
#pragma unroll
        for (int ks = 0; ks < 4; ++ks)
            qf[mt][ks] = *reinterpret_cast<const bf16x8*>(
                &Q[(size_t)(r0 + mt * 16 + ln) * DIM + ks * 32 + q8]);
#pragma unroll
        for (int r = 0; r < 4; ++r) {
            int i = r0 + mt * 16 + quad * 4 + r;
            uq[mt][r] = (int)(i64 ? u32[2 * i] : u32[i]);
        }
    }

    f32x4 o[4][8];
#pragma unroll
    for (int mt = 0; mt < 4; ++mt)
#pragma unroll
        for (int dt = 0; dt < 8; ++dt) o[mt][dt] = f32x4{0.f, 0.f, 0.f, 0.f};
    float lsum[4][4];
#pragma unroll
    for (int mt = 0; mt < 4; ++mt)
#pragma unroll
        for (int r = 0; r < 4; ++r) lsum[mt][r] = 0.f;

    unsigned short* pw = &pbuf[wave][0];

    // ---- prologue: stage tile j0 into buffer 0 (swizzled dest) ----
    {
#pragma unroll
        for (int p = 0; p < 4; ++p) {
            int slot = p * 256 + t;
            int row = slot >> 4, seg = slot & 15;
            int ss = seg ^ (row & 7);
            *reinterpret_cast<uint4*>(&kb[0][row * KROW + ss * 8]) =
                *reinterpret_cast<const uint4*>(&K[(size_t)(j0 + row) * DIM + seg * 8]);
        }
#pragma unroll
        for (int p = 0; p < 4; ++p) {
            int slot = p * 256 + t;
            int row = slot >> 3, seg = slot & 7;
            int ss = seg ^ (row & 7);
            *reinterpret_cast<uint4*>(&vb[0][row * VROW + ss * 8]) =
                *reinterpret_cast<const uint4*>(&Vt[(size_t)row * N_TOK + j0 + seg * 8]);
        }
        if (t < JT) {
            int i = j0 + t;
            ub[0][t] = (int)(i64 ? u32[2 * i] : u32[i]);
        }
    }
    __syncthreads();

    int c = 0;
    for (int j = j0; j < j1; j += JT) {
        int jn = j + JT;
        if (jn >= j1) jn = j0;   // dummy wrap on last iter

        // ---- prefetch next tile into regs (latency hides under compute) ----
        uint4 kreg[4];
#pragma unroll
        for (int p = 0; p < 4; ++p) {
            int slot = p * 256 + t;
            int row = slot >> 4, seg = slot & 15;
            kreg[p] = *reinterpret_cast<const uint4*>(&K[(size_t)(jn + row) * DIM + seg * 8]);
        }
        uint4 vreg[4];
#pragma unroll
        for (int p = 0; p < 4; ++p) {
            int slot = p * 256 + t;
            int row = slot >> 3, seg = slot & 7;
            vreg[p] = *reinterpret_cast<const uint4*>(&Vt[(size_t)row * N_TOK + jn + seg * 8]);
        }
        int ureg = 0;
        if (t < JT) ureg = (int)(i64 ? u32[2 * (jn + t)] : u32[jn + t]);

        // ---- S = Q @ K^T (64 rows x 64 cols per wave; 16 reads, 64 MFMA) ----
        f32x4 s[4][4];
#pragma unroll
        for (int mt = 0; mt < 4; ++mt)
#pragma unroll
            for (int nt = 0; nt < 4; ++nt) s[mt][nt] = f32x4{0.f, 0.f, 0.f, 0.f};
        __builtin_amdgcn_s_setprio(1);
#pragma unroll
        for (int nt = 0; nt < 4; ++nt)
#pragma unroll
            for (int ks = 0; ks < 4; ++ks) {
                int row = nt * 16 + ln;
                int sc = (ks * 4 + quad) ^ (row & 7);
                bf16x8 b = *reinterpret_cast<const bf16x8*>(&kb[c][row * KROW + sc * 8]);
                s[0][nt] = __builtin_amdgcn_mfma_f32_16x16x32_bf16(qf[0][ks], b, s[0][nt], 0, 0, 0);
                s[1][nt] = __builtin_amdgcn_mfma_f32_16x16x32_bf16(qf[1][ks], b, s[1][nt], 0, 0, 0);
                s[2][nt] = __builtin_amdgcn_mfma_f32_16x16x32_bf16(qf[2][ks], b, s[2][nt], 0, 0, 0);
                s[3][nt] = __builtin_amdgcn_mfma_f32_16x16x32_bf16(qf[3][ks], b, s[3][nt], 0, 0, 0);
            }
        __builtin_amdgcn_s_setprio(0);

        int uk[4];
#pragma unroll
        for (int nt = 0; nt < 4; ++nt) uk[nt] = ub[c][nt * 16 + ln];

        // ---- softmax + PV in two k2 halves (pbuf holds 64r x 32c at a time) ----
#pragma unroll
        for (int k2 = 0; k2 < 2; ++k2) {
            // p = exp2(s*lscale + bias) for cols [k2*32, k2*32+32) -> pbuf
#pragma unroll
            for (int mt = 0; mt < 4; ++mt)
#pragma unroll
                for (int r = 0; r < 4; ++r) {
                    int row = mt * 16 + quad * 4 + r;
                    int rx = (row >> 1) & 3;
#pragma unroll
                    for (int nh = 0; nh < 2; ++nh) {
                        int nt = k2 * 2 + nh;
                        float v = s[mt][nt][r] * lscale + (uq[mt][r] == uk[nt] ? cbias : cnob);
                        float p = exp2f(v);
                        lsum[mt][r] += p;
                        int lc = nh * 16 + ln;
                        pw[row * PROW + (((lc >> 3) ^ rx) << 3) + (lc & 7)] = f2b(p);
                    }
                }

            // pa fragments for this k2 half (per-wave pbuf: lgkm ordering)
            bf16x8 pa[4];
#pragma unroll
            for (int mt = 0; mt < 4; ++mt) {
                int row = mt * 16 + ln;
                int sc = quad ^ ((row >> 1) & 3);
                pa[mt] = *reinterpret_cast<const bf16x8*>(&pw[row * PROW + sc * 8]);
            }

            // O += P(:, k2-half) @ V(k2-half, :)  (8 reads, 32 MFMA)
            __builtin_amdgcn_s_setprio(1);
#pragma unroll
            for (int dt = 0; dt < 8; ++dt) {
                int row = dt * 16 + ln;
                int sc = (k2 * 4 + quad) ^ (row & 7);
                bf16x8 b = *reinterpret_cast<const bf16x8*>(&vb[c][row * VROW + sc * 8]);
                o[0][dt] = __builtin_amdgcn_mfma_f32_16x16x32_bf16(pa[0], b, o[0][dt], 0, 0, 0);
                o[1][dt] = __builtin_amdgcn_mfma_f32_16x16x32_bf16(pa[1], b, o[1][dt], 0, 0, 0);
                o[2][dt] = __builtin_amdgcn_mfma_f32_16x16x32_bf16(pa[2], b, o[2][dt], 0, 0, 0);
                o[3][dt] = __builtin_amdgcn_mfma_f32_16x16x32_bf16(pa[3], b, o[3][dt], 0, 0, 0);
            }
            __builtin_amdgcn_s_setprio(0);
        }

        // ---- write prefetched tile into the idle buffer (swizzled dest) ----
#pragma unroll
        for (int p = 0; p < 4; ++p) {
            int slot = p * 256 + t;
            int row = slot >> 4, seg = slot & 15;
            int ss = seg ^ (row & 7);
            *reinterpret_cast<uint4*>(&kb[c ^ 1][row * KROW + ss * 8]) = kreg[p];
        }
#pragma unroll
        for (int p = 0; p < 4; ++p) {
            int slot = p * 256 + t;
            int row = slot >> 3, seg = slot & 7;
            int ss = seg ^ (row & 7);
            *reinterpret_cast<uint4*>(&vb[c ^ 1][row * VROW + ss * 8]) = vreg[p];
        }
        if (t < JT) ub[c ^ 1][t] = ureg;

        __syncthreads();   // single barrier: c-buf reads done & c^1-buf writes visible
        c ^= 1;
    }

    // ---- epilogue: reduce l across the 16 lanes of each row ----
#pragma unroll
    for (int mt = 0; mt < 4; ++mt)
#pragma unroll
        for (int r = 0; r < 4; ++r) {
            float l = lsum[mt][r];
            l += __shfl_xor(l, 1, 64);
            l += __shfl_xor(l, 2, 64);
            l += __shfl_xor(l, 4, 64);
            l += __shfl_xor(l, 8, 64);
            lsum[mt][r] = l;
        }

    if (out != nullptr) {
#pragma unroll
        for (int mt = 0; mt < 4; ++mt)
#pragma unroll
            for (int r = 0; r < 4; ++r) {
                float l = lsum[mt][r];
                bool lbad = !(l > 0.f) || !(l < 3.0e38f);
                float inv = 1.0f / l;
                int row = r0 + mt * 16 + quad * 4 + r;
#pragma unroll
                for (int dt = 0; dt < 8; ++dt) {
                    float v = o[mt][dt][r] * inv;
                    if (v != v) v = 12345.0f;
                    if (lbad)   v = 23456.0f;
                    out[(size_t)row * DIM + dt * 16 + ln] = v;
                }
            }
    } else {
        const size_t base = (size_t)split * N_TOK;
#pragma unroll
        for (int mt = 0; mt < 4; ++mt) {
#pragma unroll
            for (int r = 0; r < 4; ++r) {
                int row = r0 + mt * 16 + quad * 4 + r;
#pragma unroll
                for (int dt = 0; dt < 8; ++dt)
                    pO[(base + row) * DIM + dt * 16 + ln] = o[mt][dt][r];
                if (ln == 0)
                    pl[base + row] = lsum[mt][r];
            }
        }
    }
}

// ---------------------------------------------------------------------------
// Merge: out[row] = (sum_s pO[s][row]) / (sum_s pl[s][row]).
// ---------------------------------------------------------------------------
__global__ __launch_bounds__(256)
void merge_kernel(const float* __restrict__ pO, const float* __restrict__ pl,
                  float* __restrict__ out, int ns)
{
    const int t = threadIdx.x;
    const int wave = t >> 6, lane = t & 63;
    const int row = blockIdx.x * 4 + wave;
    const int c = lane * 2;

    float l = 0.f;
    for (int s = 0; s < ns; ++s) l += pl[(size_t)s * N_TOK + row];
    bool lbad = !(l > 0.f) || !(l < 3.0e38f);
    float inv = 1.0f / l;

    float a0 = 0.f, a1 = 0.f;
    for (int s = 0; s < ns; ++s) {
        const float2 v = *reinterpret_cast<const float2*>(
            &pO[((size_t)s * N_TOK + row) * DIM + c]);
        a0 += v.x; a1 += v.y;
    }
    float v0 = a0 * inv, v1 = a1 * inv;
    if (v0 != v0) v0 = 12345.0f;
    if (v1 != v1) v1 = 12345.0f;
    if (lbad) { v0 = 23456.0f; v1 = 23456.0f; }
    float2 res; res.x = v0; res.y = v1;
    *reinterpret_cast<float2*>(&out[(size_t)row * DIM + c]) = res;
}

// ---------------------------------------------------------------------------
extern "C" void kernel_launch(void* const* d_in, const int* in_sizes, int n_in,
                              void* d_out, int out_size, void* d_ws, size_t ws_size,
                              hipStream_t stream)
{
    float* out = (float*)d_out;

    bool ok = (n_in == 5) &&
              in_sizes[0] == N_TOK * DIM && in_sizes[1] == N_TOK &&
              in_sizes[2] == DIM * DIM && in_sizes[3] == DIM * DIM &&
              in_sizes[4] == DIM * DIM && out_size == N_TOK * DIM;
    if (!ok) { marker_kernel<<<8192, 256, 0, stream>>>(out, 5555.f); return; }

    const float*        xf  = (const float*)d_in[0];
    const unsigned int* u32 = (const unsigned int*)d_in[1];
    const float*        wqf = (const float*)d_in[2];
    const float*        wkf = (const float*)d_in[3];
    const float*        wvf = (const float*)d_in[4];

    char* ws = (char*)d_ws;
    size_t off = 0;
    unsigned short* Q  = (unsigned short*)(ws + off); off += (size_t)N_TOK * DIM * 2;  // 4 MB
    unsigned short* K  = (unsigned short*)(ws + off); off += (size_t)N_TOK * DIM * 2;  // 4 MB
    unsigned short* Vt = (unsigned short*)(ws + off); off += (size_t)N_TOK * DIM * 2;  // 4 MB

    if (ws_size < off) { marker_kernel<<<8192, 256, 0, stream>>>(out, 4444.f); return; }

    // nsplit=4: grid 256 blocks = 1 block/CU (v5 is 256 Q-rows/block).
    const size_t per_split = (size_t)N_TOK * DIM * 4 + (size_t)N_TOK * 4;
    int nsplit = 1;
    if (ws_size >= off + 4 * per_split)      nsplit = 4;
    else if (ws_size >= off + 2 * per_split) nsplit = 2;

    qkv_kernel<<<dim3(N_TOK / 64, 3), 256, 0, stream>>>(xf, wqf, wkf, wvf, Q, K, Vt);

    if (nsplit >= 2) {
        float* pO = (float*)(ws + off);
        float* pl = (float*)(ws + off + (size_t)nsplit * N_TOK * DIM * 4);
        flash_kernel<<<dim3(N_TOK / 256, nsplit), 256, 0, stream>>>(
            Q, K, Vt, u32, N_TOK / nsplit, pO, pl, nullptr);
        merge_kernel<<<N_TOK / 4, 256, 0, stream>>>(pO, pl, out, nsplit);
    } else {
        flash_kernel<<<dim3(N_TOK / 256, 1), 256, 0, stream>>>(
            Q, K, Vt, u32, N_TOK, nullptr, nullptr, out);
    }
}

// Round 8
// 291.131 us; speedup vs baseline: 1.6882x; 1.6882x over previous
//
#include <hip/hip_runtime.h>
#include <hip/hip_bf16.h>

#define N_TOK 16384
#define DIM   128
#define JT     64      // K/V tile (j) per iteration

// LDS row strides (shorts), unpadded + XOR swizzle (T2): 16B-seg ^= (row&7).
// Consecutive lanes read consecutive rows -> any 8-lane phase hits 8 distinct
// segs -> conflict-free (m136 phase model).
#define KROW 128       // kbuf rows: 64 (kv-major, [kv][d])
#define VROW 64        // vbuf rows: 128 (d-major,  [d][kv])

using bf16x8 = __attribute__((ext_vector_type(8)))  short;  // 8 bf16 (MFMA A/B frag)
using f32x4  = __attribute__((ext_vector_type(4)))  float;
using f32x16 = __attribute__((ext_vector_type(16))) float;  // 32x32 MFMA C/D frag
using i32x4  = __attribute__((ext_vector_type(4)))  int;

static __device__ __forceinline__ unsigned short f2b(float f) {
    union { __hip_bfloat16 h; unsigned short u; } cv;
    cv.h = __float2bfloat16(f);   // RNE
    return cv.u;
}

static __device__ __forceinline__ bf16x8 load8f(const float* p) {
    float4 a = *reinterpret_cast<const float4*>(p);
    float4 b = *reinterpret_cast<const float4*>(p + 4);
    bf16x8 r;
    r[0] = (short)f2b(a.x); r[1] = (short)f2b(a.y);
    r[2] = (short)f2b(a.z); r[3] = (short)f2b(a.w);
    r[4] = (short)f2b(b.x); r[5] = (short)f2b(b.y);
    r[6] = (short)f2b(b.z); r[7] = (short)f2b(b.w);
    return r;
}

// ---------------------------------------------------------------------------
__global__ __launch_bounds__(256)
void marker_kernel(float* out, float val)
{
    int i = blockIdx.x * 256 + threadIdx.x;
    if (i < N_TOK * DIM) out[i] = val;
}

// ---------------------------------------------------------------------------
// QKV: Q = x@Wq^T, K = x@Wk^T, Vt = (x@Wv^T)^T.  fp32 in, bf16 out (ws).
// ---------------------------------------------------------------------------
__global__ __launch_bounds__(256)
void qkv_kernel(const float* __restrict__ x,
                const float* __restrict__ wq,
                const float* __restrict__ wk,
                const float* __restrict__ wv,
                unsigned short* __restrict__ Q,
                unsigned short* __restrict__ K,
                unsigned short* __restrict__ Vt)
{
    const int t = threadIdx.x;
    const int wave = t >> 6, lane = t & 63;
    const int ln = lane & 15, quad = lane >> 4, q8 = quad * 8;
    const int z = blockIdx.y;
    const float* W = (z == 0) ? wq : (z == 1) ? wk : wv;
    const int r0 = blockIdx.x * 64 + wave * 16;

    bf16x8 a[4];
#pragma unroll
    for (int ks = 0; ks < 4; ++ks)
        a[ks] = load8f(&x[(size_t)(r0 + ln) * DIM + ks * 32 + q8]);

    f32x4 acc[8];
#pragma unroll
    for (int nt = 0; nt < 8; ++nt) acc[nt] = f32x4{0.f, 0.f, 0.f, 0.f};

#pragma unroll
    for (int nt = 0; nt < 8; ++nt)
#pragma unroll
        for (int ks = 0; ks < 4; ++ks) {
            bf16x8 b = load8f(&W[(size_t)(nt * 16 + ln) * DIM + ks * 32 + q8]);
            acc[nt] = __builtin_amdgcn_mfma_f32_16x16x32_bf16(a[ks], b, acc[nt], 0, 0, 0);
        }

#pragma unroll
    for (int nt = 0; nt < 8; ++nt) {
        const int col = nt * 16 + ln;
        if (z == 2) {
            ushort4 v4;
            v4.x = f2b(acc[nt][0]); v4.y = f2b(acc[nt][1]);
            v4.z = f2b(acc[nt][2]); v4.w = f2b(acc[nt][3]);
            *reinterpret_cast<ushort4*>(&Vt[(size_t)col * N_TOK + r0 + quad * 4]) = v4;
        } else {
            unsigned short* dst = (z == 0) ? Q : K;
#pragma unroll
            for (int r = 0; r < 4; ++r)
                dst[(size_t)(r0 + quad * 4 + r) * DIM + col] = f2b(acc[nt][r]);
        }
    }
}

// ---------------------------------------------------------------------------
// Flash attention v6: 32x32 MFMA, SWAPPED QK^T, in-register softmax (T12).
// Macro-structure identical to v3 (proven 234us): 4 waves x 256 thr,
// 128 Q-rows/block (32/wave), grid (128, nsplit), dbuf K/V/u, 1 barrier/tile.
//
// Swapped QK^T: S^T = mfma_32x32x16(A=K, B=Q): D[m=kv][n=q].
// C-layout (m74/m101): col=lane&31 -> q-row; row=crow(reg,hi)=(reg&3)+8*(reg>>2)+4*hi
// with hi=lane>>5.  So lane owns P[q=lane&31][kv = 32*kv32 + crow] -- a full
// q-row slice; softmax is per-lane register math (no LDS round-trip, no max
// needed: fixed-offset exp2(s*lscale - 16 + bias)).
//
// P -> PV A-frag: A[m=q=lane&31][k=16*ktg + 8*hi + j].  Decompose owned
// k = 8g+4h'+i (h'=owner hi, g=0..3, i=0..3): frag(ktg=2kv32+kt) = first 4
// from (h'=0, g=2kt+hi), last 4 from (h'=1, g=2kt+hi).  Each lane keeps
// (h'=hi, g=2kt+hi... its complement) and receives the partner half via ONE
// shfl_xor(32) per dword: send = hi ? dw[2kt] : dw[2kt+1]; kept = the other;
// frag = hi ? {recv, kept} : {kept, recv}.  8 shfl + selects per tile.
//
// PV: mfma_32x32x16(A=pa[ktg], B=V-frag): B[n=d=32nt+lane&31][k=kv] read from
// vb[d][kv] rows -> contiguous b128 (existing Vt layout).  O: D[m=q][n=d]:
// lane holds 16 q-rows (crow) x 4 d-cols per nt.  l-normalization redistributed
// through a tiny per-wave lbuf (q=lane&31 -> crow rows).
// ---------------------------------------------------------------------------
__global__ __launch_bounds__(256, 2)
void flash_kernel(const unsigned short* __restrict__ Q,
                  const unsigned short* __restrict__ K,
                  const unsigned short* __restrict__ Vt,
                  const unsigned int* __restrict__ u32,
                  int jspan,
                  float* __restrict__ pO, float* __restrict__ pl,
                  float* __restrict__ out)
{
    __shared__ __align__(16) unsigned short kb[2][JT * KROW];   // 32 KB
    __shared__ __align__(16) unsigned short vb[2][DIM * VROW];  // 32 KB
    __shared__ __align__(16) int   ub[2][JT];                   // 512 B
    __shared__ __align__(16) float lbuf[4][32];                 // 512 B -> 66.5 KB

    const int t = threadIdx.x;
    const int wave = t >> 6, lane = t & 63;
    const int q31 = lane & 31, hi = lane >> 5;
    const int r0w = blockIdx.x * 128 + wave * 32;    // this wave's q-base
    const int split = blockIdx.y;
    const int j0 = split * jspan;
    const int j1 = j0 + jspan;

    const float lscale = 1.4426950408889634f * 0.08838834764831845f; // log2(e)/sqrt(128)
    const float cbias  = 5.0f * 1.4426950408889634f - 16.0f;         // same-user
    const float cnob   = -16.0f;                                     // different user

    // uid dtype sniff (uniform verdict on every thread)
    bool i64 = true;
    for (int k = 0; k < 64; ++k) i64 = i64 && (u32[2 * k + 1] == 0u);

    // Q fragments: B[n=q31][k = dt*16 + hi*8 + j]
    bf16x8 qf[8];
#pragma unroll
    for (int dt = 0; dt < 8; ++dt)
        qf[dt] = *reinterpret_cast<const bf16x8*>(
            &Q[(size_t)(r0w + q31) * DIM + dt * 16 + hi * 8]);

    const int uq = (int)(i64 ? u32[2 * (r0w + q31)] : u32[r0w + q31]);

    f32x16 o[4];
#pragma unroll
    for (int nt = 0; nt < 4; ++nt)
#pragma unroll
        for (int r = 0; r < 16; ++r) o[nt][r] = 0.f;
    float lsum = 0.f;

    // ---- prologue: stage tile j0 into buffer 0 (swizzled dest) ----
    {
#pragma unroll
        for (int p = 0; p < 4; ++p) {
            int slot = p * 256 + t;
            int row = slot >> 4, seg = slot & 15;
            int ss = seg ^ (row & 7);
            *reinterpret_cast<uint4*>(&kb[0][row * KROW + ss * 8]) =
                *reinterpret_cast<const uint4*>(&K[(size_t)(j0 + row) * DIM + seg * 8]);
        }
#pragma unroll
        for (int p = 0; p < 4; ++p) {
            int slot = p * 256 + t;
            int row = slot >> 3, seg = slot & 7;
            int ss = seg ^ (row & 7);
            *reinterpret_cast<uint4*>(&vb[0][row * VROW + ss * 8]) =
                *reinterpret_cast<const uint4*>(&Vt[(size_t)row * N_TOK + j0 + seg * 8]);
        }
        if (t < JT) {
            int i = j0 + t;
            ub[0][t] = (int)(i64 ? u32[2 * i] : u32[i]);
        }
    }
    __syncthreads();

    int c = 0;
    for (int j = j0; j < j1; j += JT) {
        int jn = j + JT;
        if (jn >= j1) jn = j0;   // dummy wrap on last iter

        // ---- prefetch next tile into regs ----
        uint4 kreg[4];
#pragma unroll
        for (int p = 0; p < 4; ++p) {
            int slot = p * 256 + t;
            int row = slot >> 4, seg = slot & 15;
            kreg[p] = *reinterpret_cast<const uint4*>(&K[(size_t)(jn + row) * DIM + seg * 8]);
        }
        uint4 vreg[4];
#pragma unroll
        for (int p = 0; p < 4; ++p) {
            int slot = p * 256 + t;
            int row = slot >> 3, seg = slot & 7;
            vreg[p] = *reinterpret_cast<const uint4*>(&Vt[(size_t)row * N_TOK + jn + seg * 8]);
        }
        int ureg = 0;
        if (t < JT) ureg = (int)(i64 ? u32[2 * (jn + t)] : u32[jn + t]);

        // ---- swapped QK^T: s[kv32] = K-rows x Q-rows (D accumulated over 8 dt) ----
        f32x16 s0v, s1v;
#pragma unroll
        for (int r = 0; r < 16; ++r) { s0v[r] = 0.f; s1v[r] = 0.f; }
        __builtin_amdgcn_s_setprio(1);
#pragma unroll
        for (int dt = 0; dt < 8; ++dt) {
            int seg = (dt * 2 + hi) ^ (q31 & 7);     // (32+q31)&7 == q31&7
            bf16x8 k0 = *reinterpret_cast<const bf16x8*>(&kb[c][q31 * KROW + seg * 8]);
            bf16x8 k1 = *reinterpret_cast<const bf16x8*>(&kb[c][(32 + q31) * KROW + seg * 8]);
            s0v = __builtin_amdgcn_mfma_f32_32x32x16_bf16(k0, qf[dt], s0v, 0, 0, 0);
            s1v = __builtin_amdgcn_mfma_f32_32x32x16_bf16(k1, qf[dt], s1v, 0, 0, 0);
        }
        __builtin_amdgcn_s_setprio(0);

        // ---- softmax + pack + half-wave exchange -> pa[4] ----
        bf16x8 pa[4];
#pragma unroll
        for (int kv32 = 0; kv32 < 2; ++kv32) {
            // uid regs in the crow layout: k = 32*kv32 + 8g + 4hi + i
            i32x4 ukg[4];
#pragma unroll
            for (int g = 0; g < 4; ++g)
                ukg[g] = *reinterpret_cast<const i32x4*>(&ub[c][32 * kv32 + 8 * g + 4 * hi]);

            unsigned int dw[4][2];
#pragma unroll
            for (int g = 0; g < 4; ++g) {
                float p0, p1, p2, p3;
                {
                    float v0 = __builtin_fmaf((kv32 ? s1v : s0v)[4 * g + 0], lscale,
                                              (uq == ukg[g][0]) ? cbias : cnob);
                    float v1 = __builtin_fmaf((kv32 ? s1v : s0v)[4 * g + 1], lscale,
                                              (uq == ukg[g][1]) ? cbias : cnob);
                    float v2 = __builtin_fmaf((kv32 ? s1v : s0v)[4 * g + 2], lscale,
                                              (uq == ukg[g][2]) ? cbias : cnob);
                    float v3 = __builtin_fmaf((kv32 ? s1v : s0v)[4 * g + 3], lscale,
                                              (uq == ukg[g][3]) ? cbias : cnob);
                    p0 = exp2f(v0); p1 = exp2f(v1); p2 = exp2f(v2); p3 = exp2f(v3);
                }
                lsum += (p0 + p1) + (p2 + p3);
                dw[g][0] = (unsigned int)f2b(p0) | ((unsigned int)f2b(p1) << 16);
                dw[g][1] = (unsigned int)f2b(p2) | ((unsigned int)f2b(p3) << 16);
            }

            // exchange: frag(kt) = first-half h'=0 data, second-half h'=1 data
#pragma unroll
            for (int kt = 0; kt < 2; ++kt) {
                unsigned int s0d = hi ? dw[2 * kt][0] : dw[2 * kt + 1][0];
                unsigned int s1d = hi ? dw[2 * kt][1] : dw[2 * kt + 1][1];
                unsigned int r0d = (unsigned int)__shfl_xor((int)s0d, 32, 64);
                unsigned int r1d = (unsigned int)__shfl_xor((int)s1d, 32, 64);
                unsigned int k0d = hi ? dw[2 * kt + 1][0] : dw[2 * kt][0];
                unsigned int k1d = hi ? dw[2 * kt + 1][1] : dw[2 * kt][1];
                union { unsigned int u[4]; bf16x8 v; } pu;
                pu.u[0] = hi ? r0d : k0d;
                pu.u[1] = hi ? r1d : k1d;
                pu.u[2] = hi ? k0d : r0d;
                pu.u[3] = hi ? k1d : r1d;
                pa[kv32 * 2 + kt] = pu.v;
            }
        }

        // ---- write prefetched K/u into idle buffer (kreg dead after this) ----
#pragma unroll
        for (int p = 0; p < 4; ++p) {
            int slot = p * 256 + t;
            int row = slot >> 4, seg = slot & 15;
            int ss = seg ^ (row & 7);
            *reinterpret_cast<uint4*>(&kb[c ^ 1][row * KROW + ss * 8]) = kreg[p];
        }
        if (t < JT) ub[c ^ 1][t] = ureg;

        // ---- PV: O[q][d] += P @ V  (B[n=d][k=kv] from vb rows) ----
        __builtin_amdgcn_s_setprio(1);
#pragma unroll
        for (int nt = 0; nt < 4; ++nt) {
            int row = nt * 32 + q31;                 // d-row of vb; row&7 == q31&7
#pragma unroll
            for (int ktg = 0; ktg < 4; ++ktg) {
                int seg = (ktg * 2 + hi) ^ (q31 & 7);
                bf16x8 b = *reinterpret_cast<const bf16x8*>(&vb[c][row * VROW + seg * 8]);
                o[nt] = __builtin_amdgcn_mfma_f32_32x32x16_bf16(pa[ktg], b, o[nt], 0, 0, 0);
            }
        }
        __builtin_amdgcn_s_setprio(0);

        // ---- write prefetched V into idle buffer ----
#pragma unroll
        for (int p = 0; p < 4; ++p) {
            int slot = p * 256 + t;
            int row = slot >> 3, seg = slot & 7;
            int ss = seg ^ (row & 7);
            *reinterpret_cast<uint4*>(&vb[c ^ 1][row * VROW + ss * 8]) = vreg[p];
        }

        __syncthreads();   // single barrier per tile
        c ^= 1;
    }

    // ---- epilogue ----
    lsum += __shfl_xor(lsum, 32, 64);   // combine the two k-halves of q=q31

    if (out != nullptr) {
        bool lbad = !(lsum > 0.f) || !(lsum < 3.0e38f);
        float inv = 1.0f / lsum;
        if (hi == 0) lbuf[wave][q31] = lbad ? -1.0f : inv;
        __syncthreads();
        f32x4 ivg[4];
#pragma unroll
        for (int g = 0; g < 4; ++g)
            ivg[g] = *reinterpret_cast<const f32x4*>(&lbuf[wave][8 * g + 4 * hi]);
#pragma unroll
        for (int nt = 0; nt < 4; ++nt)
#pragma unroll
            for (int g = 0; g < 4; ++g)
#pragma unroll
                for (int i = 0; i < 4; ++i) {
                    int row = r0w + 8 * g + 4 * hi + i;
                    float iv = ivg[g][i];
                    float v = o[nt][4 * g + i] * iv;
                    if (v != v) v = 12345.0f;
                    if (iv < 0.f) v = 23456.0f;
                    out[(size_t)row * DIM + nt * 32 + q31] = v;
                }
    } else {
        const size_t base = (size_t)split * N_TOK;
        if (hi == 0) pl[base + r0w + q31] = lsum;
#pragma unroll
        for (int nt = 0; nt < 4; ++nt)
#pragma unroll
            for (int g = 0; g < 4; ++g)
#pragma unroll
                for (int i = 0; i < 4; ++i) {
                    int row = r0w + 8 * g + 4 * hi + i;
                    pO[(base + row) * DIM + nt * 32 + q31] = o[nt][4 * g + i];
                }
    }
}

// ---------------------------------------------------------------------------
// Merge: out[row] = (sum_s pO[s][row]) / (sum_s pl[s][row]).
// ---------------------------------------------------------------------------
__global__ __launch_bounds__(256)
void merge_kernel(const float* __restrict__ pO, const float* __restrict__ pl,
                  float* __restrict__ out, int ns)
{
    const int t = threadIdx.x;
    const int wave = t >> 6, lane = t & 63;
    const int row = blockIdx.x * 4 + wave;
    const int c = lane * 2;

    float l = 0.f;
    for (int s = 0; s < ns; ++s) l += pl[(size_t)s * N_TOK + row];
    bool lbad = !(l > 0.f) || !(l < 3.0e38f);
    float inv = 1.0f / l;

    float a0 = 0.f, a1 = 0.f;
    for (int s = 0; s < ns; ++s) {
        const float2 v = *reinterpret_cast<const float2*>(
            &pO[((size_t)s * N_TOK + row) * DIM + c]);
        a0 += v.x; a1 += v.y;
    }
    float v0 = a0 * inv, v1 = a1 * inv;
    if (v0 != v0) v0 = 12345.0f;
    if (v1 != v1) v1 = 12345.0f;
    if (lbad) { v0 = 23456.0f; v1 = 23456.0f; }
    float2 res; res.x = v0; res.y = v1;
    *reinterpret_cast<float2*>(&out[(size_t)row * DIM + c]) = res;
}

// ---------------------------------------------------------------------------
extern "C" void kernel_launch(void* const* d_in, const int* in_sizes, int n_in,
                              void* d_out, int out_size, void* d_ws, size_t ws_size,
                              hipStream_t stream)
{
    float* out = (float*)d_out;

    bool ok = (n_in == 5) &&
              in_sizes[0] == N_TOK * DIM && in_sizes[1] == N_TOK &&
              in_sizes[2] == DIM * DIM && in_sizes[3] == DIM * DIM &&
              in_sizes[4] == DIM * DIM && out_size == N_TOK * DIM;
    if (!ok) { marker_kernel<<<8192, 256, 0, stream>>>(out, 5555.f); return; }

    const float*        xf  = (const float*)d_in[0];
    const unsigned int* u32 = (const unsigned int*)d_in[1];
    const float*        wqf = (const float*)d_in[2];
    const float*        wkf = (const float*)d_in[3];
    const float*        wvf = (const float*)d_in[4];

    char* ws = (char*)d_ws;
    size_t off = 0;
    unsigned short* Q  = (unsigned short*)(ws + off); off += (size_t)N_TOK * DIM * 2;  // 4 MB
    unsigned short* K  = (unsigned short*)(ws + off); off += (size_t)N_TOK * DIM * 2;  // 4 MB
    unsigned short* Vt = (unsigned short*)(ws + off); off += (size_t)N_TOK * DIM * 2;  // 4 MB

    if (ws_size < off) { marker_kernel<<<8192, 256, 0, stream>>>(out, 4444.f); return; }

    // nsplit=4 proven best (R1/R2); grid (128,4) = 512 blocks = 2/CU.
    const size_t per_split = (size_t)N_TOK * DIM * 4 + (size_t)N_TOK * 4;
    int nsplit = 1;
    if (ws_size >= off + 4 * per_split)      nsplit = 4;
    else if (ws_size >= off + 2 * per_split) nsplit = 2;

    qkv_kernel<<<dim3(N_TOK / 64, 3), 256, 0, stream>>>(xf, wqf, wkf, wvf, Q, K, Vt);

    if (nsplit >= 2) {
        float* pO = (float*)(ws + off);
        float* pl = (float*)(ws + off + (size_t)nsplit * N_TOK * DIM * 4);
        flash_kernel<<<dim3(N_TOK / 128, nsplit), 256, 0, stream>>>(
            Q, K, Vt, u32, N_TOK / nsplit, pO, pl, nullptr);
        merge_kernel<<<N_TOK / 4, 256, 0, stream>>>(pO, pl, out, nsplit);
    } else {
        flash_kernel<<<dim3(N_TOK / 128, 1), 256, 0, stream>>>(
            Q, K, Vt, u32, N_TOK, nullptr, nullptr, out);
    }
}